// Round 6
// baseline (600.791 us; speedup 1.0000x reference)
//
#include <hip/hip_runtime.h>
#include <hip/hip_bf16.h>

#define NNODES 50000
#define NEDGES 800000
#define EB 1024          // edge grid: 4 blocks/CU resident
#define SCAN_BLOCKS 196  // ceil(50000/256)
#define TRN_BLOCKS 256   // 4 x 128x128 transposes / 256
#define GP_BLOCKS 782    // ceil(50000/64)

typedef short bf16x8 __attribute__((ext_vector_type(8)));
typedef float f32x4 __attribute__((ext_vector_type(4)));
typedef unsigned short u16;
typedef unsigned int u32;

__device__ __forceinline__ u16 f2bf(float f) {
    __hip_bfloat16 b = __float2bfloat16(f);
    return *reinterpret_cast<u16*>(&b);
}
__device__ __forceinline__ float bf2f(u16 v) {
    u32 u = ((u32)v) << 16;
    return __uint_as_float(u);
}
__device__ __forceinline__ u32 pack2(float a, float b) {
    __hip_bfloat162 t = __float22bfloat162_rn(float2{a, b});
    return *reinterpret_cast<u32*>(&t);
}
__device__ __forceinline__ float fast_silu(float x) {
    float e = __builtin_amdgcn_exp2f(-1.442695040888963f * x);
    return x * __builtin_amdgcn_rcpf(1.0f + e);
}
__device__ __forceinline__ bf16x8 ld8(const u16* p) {
    return *(const bf16x8*)p;
}
__device__ __forceinline__ f32x4 mfma16(bf16x8 a, bf16x8 b, f32x4 c) {
    return __builtin_amdgcn_mfma_f32_16x16x32_bf16(a, b, c, 0, 0, 0);
}

// ---- prep: 4 128x128 transposes (fp32->bf16) + receiver histogram ----
__global__ void prep_kernel(const float* __restrict__ eW2, const float* __restrict__ pW1,
                            const float* __restrict__ nW1, const float* __restrict__ nW2,
                            u16* __restrict__ eW2T, u16* __restrict__ pW1T,
                            u16* __restrict__ nW1bT, u16* __restrict__ nW2T,
                            const int* __restrict__ rcv, int* __restrict__ counts) {
    int b = blockIdx.x;
    if (b < TRN_BLOCKS) {
        int i = b * 256 + threadIdx.x;   // 0..65535
        int which = i >> 14, local = i & 16383;
        int c = local >> 7, k = local & 127;
        const float* src; u16* dst; int koff = 0;
        if (which == 0)      { src = eW2; dst = eW2T; }
        else if (which == 1) { src = pW1; dst = pW1T; }
        else if (which == 2) { src = nW1; dst = nW1bT; koff = 128; }
        else                 { src = nW2; dst = nW2T; }
        dst[local] = f2bf(src[(koff + k) * 128 + c]);
    } else {
        int e = (b - TRN_BLOCKS) * 256 + threadIdx.x;
        if (e < NEDGES) atomicAdd(&counts[rcv[e]], 1);
    }
}

// ---- chained single-pass exclusive scan (decoupled lookback, 196 blocks) ----
__global__ __launch_bounds__(256) void scan_chained(const int* __restrict__ counts,
                                                    int* __restrict__ cursor,
                                                    int* __restrict__ flags) {
    __shared__ int stmp[256];
    __shared__ int sprev;
    int tx = threadIdx.x, b = blockIdx.x;
    int i = b * 256 + tx;
    int v = (i < NNODES) ? counts[i] : 0;
    stmp[tx] = v;
    __syncthreads();
    for (int off = 1; off < 256; off <<= 1) {
        int t = (tx >= off) ? stmp[tx - off] : 0;
        __syncthreads();
        stmp[tx] += t;
        __syncthreads();
    }
    int incl = stmp[tx], total = stmp[255];
    if (tx == 0) {
        int prevsum = 0;
        if (b > 0) {
            int f;
            while ((f = __hip_atomic_load(&flags[b - 1], __ATOMIC_RELAXED,
                                          __HIP_MEMORY_SCOPE_AGENT)) == 0)
                __builtin_amdgcn_s_sleep(2);
            prevsum = f - 1;
        }
        __hip_atomic_store(&flags[b], prevsum + total + 1, __ATOMIC_RELAXED,
                           __HIP_MEMORY_SCOPE_AGENT);
        sprev = prevsum;
    }
    __syncthreads();
    if (i < NNODES) cursor[i] = sprev + incl - v;
}

__global__ void scatter_kernel(const int* __restrict__ rcv, int* __restrict__ cursor,
                               int* __restrict__ perm) {
    int e = blockIdx.x * 256 + threadIdx.x;
    if (e < NEDGES) {
        int p = atomicAdd(&cursor[rcv[e]], 1);
        perm[p] = e;
    }
}

// ---- P precompute: P[n] = [h@eW1a + eb1/2 | h@eW1b + eb1/2 | h@nW1a] (bf16) ----
// B-fragments gathered directly from fp32 weights (one-time, removes transpose dep).
__global__ __launch_bounds__(256) void gemm_p(
    const float* __restrict__ h, const float* __restrict__ eW1,
    const float* __restrict__ nW1, const float* __restrict__ eb1,
    u16* __restrict__ P)
{
    const int tid  = threadIdx.x;
    const int w    = tid >> 6;
    const int lane = tid & 63;
    const int m    = lane & 15;
    const int quad = lane >> 4;
    const int ksub = quad * 8;

    bf16x8 bw[4][6];
    float bias[6];
    #pragma unroll
    for (int cc = 0; cc < 6; cc++) {
        int C = 96 * w + 16 * cc + m;
        const float* src; int koff, c;
        if (C < 128)      { src = eW1; koff = 0;   c = C;       bias[cc] = 0.5f * eb1[C]; }
        else if (C < 256) { src = eW1; koff = 128; c = C - 128; bias[cc] = 0.5f * eb1[C - 128]; }
        else              { src = nW1; koff = 0;   c = C - 256; bias[cc] = 0.f; }
        #pragma unroll
        for (int t = 0; t < 4; t++)
            #pragma unroll
            for (int j = 0; j < 8; j++)
                bw[t][cc][j] = (short)f2bf(src[(koff + t * 32 + ksub + j) * 128 + c]);
    }
    const int base = blockIdx.x * 64;
    #pragma unroll
    for (int mt = 0; mt < 4; mt++) {
        int nm = base + mt * 16 + m;
        if (nm >= NNODES) nm = NNODES - 1;
        bf16x8 afr[4];
        #pragma unroll
        for (int t = 0; t < 4; t++) {
            const float* ap = h + (size_t)nm * 128 + t * 32 + ksub;
            f32x4 lo = *(const f32x4*)ap;
            f32x4 hi = *(const f32x4*)(ap + 4);
            #pragma unroll
            for (int j = 0; j < 4; j++) {
                afr[t][j]     = (short)f2bf(lo[j]);
                afr[t][4 + j] = (short)f2bf(hi[j]);
            }
        }
        f32x4 acc[6];
        #pragma unroll
        for (int cc = 0; cc < 6; cc++) acc[cc] = (f32x4){0,0,0,0};
        #pragma unroll
        for (int t = 0; t < 4; t++)
            #pragma unroll
            for (int cc = 0; cc < 6; cc++)
                acc[cc] = mfma16(afr[t], bw[t][cc], acc[cc]);
        #pragma unroll
        for (int cc = 0; cc < 6; cc++) {
            int C = 96 * w + 16 * cc + m;
            #pragma unroll
            for (int r = 0; r < 4; r++) {
                int nr = base + mt * 16 + quad * 4 + r;
                if (nr < NNODES) P[(size_t)nr * 384 + C] = f2bf(acc[cc][r] + bias[cc]);
            }
        }
    }
}

struct __align__(16) EdgeLds {
    u16   m1[64 * 136];       // layer1 out (swizzled); REUSED as msgT[col][68] after layer2
    u16   msg[64 * 136];      // row-major msg
    float diff[64][4];
    float pcpart[4][64];
    float wlast[128];
    float radial[64];
    int   sndloc[64];
    int   rcvloc[64];
    u32   segmask[2];
};

__global__ __launch_bounds__(256, 4) void edge_kernel(
    const u16* __restrict__ P, const float* __restrict__ pos,
    const int* __restrict__ snd, const int* __restrict__ rcv,
    const int* __restrict__ perm,
    const float* __restrict__ eW1last,
    const u16* __restrict__ eW2T, const float* __restrict__ eb2,
    const u16* __restrict__ pW1T, const float* __restrict__ pb1,
    const float* __restrict__ pW2,
    float* __restrict__ agg, float* __restrict__ posacc)
{
    __shared__ EdgeLds S;
    const int tid  = threadIdx.x;
    const int w    = tid >> 6;
    const int lane = tid & 63;
    const int m    = lane & 15;
    const int quad = lane >> 4;
    const int ksub = quad * 8;

    bf16x8 bw2[4][2], bp1[4][2];
    float b2v[2], pb1v[2], pw2v[2];
    #pragma unroll
    for (int cc = 0; cc < 2; cc++) {
        int col = (2 * w + cc) * 16 + m;
        #pragma unroll
        for (int t = 0; t < 4; t++) {
            bw2[t][cc] = ld8(eW2T + col * 128 + t * 32 + ksub);
            bp1[t][cc] = ld8(pW1T + col * 128 + t * 32 + ksub);
        }
        b2v[cc]  = eb2[col];
        pb1v[cc] = pb1[col];
        pw2v[cc] = pW2[col];
    }
    if (tid < 128) S.wlast[tid] = eW1last[tid];

    for (int base = blockIdx.x * 64; base < NEDGES; base += gridDim.x * 64) {
        __syncthreads();
        int eg = perm[base + lane];
        int s = snd[eg], r = rcv[eg];
        if (tid < 64) {
            S.sndloc[tid] = s; S.rcvloc[tid] = r;
            float rad = 0.f;
            #pragma unroll
            for (int c = 0; c < 3; c++) {
                float d = pos[s * 3 + c] - pos[r * 3 + c];
                S.diff[tid][c] = d;
                rad += d * d;
            }
            S.radial[tid] = rad;
            int prevr = __shfl_up(r, 1);
            unsigned long long bm = __ballot((lane == 0) || (r != prevr));
            if (lane == 0) { S.segmask[0] = (u32)bm; S.segmask[1] = (u32)(bm >> 32); }
        }
        __syncthreads();
        // ---- layer1: m1 = silu(Pa[s] + Pb[r] + rad*wlast)  (bias pre-folded) ----
        {
            float rad = S.radial[lane];
            const u16* pa = P + (size_t)s * 384 + w * 32;
            const u16* pb = P + (size_t)r * 384 + 128 + w * 32;
            const int sw = lane >> 3;
            #pragma unroll
            for (int k = 0; k < 4; k++) {
                bf16x8 va = ld8(pa + k * 8);
                bf16x8 vb = ld8(pb + k * 8);
                u32 pk[4];
                #pragma unroll
                for (int jj = 0; jj < 4; jj++) {
                    int col = w * 32 + k * 8 + jj * 2;
                    float2 wl = *(const float2*)&S.wlast[col];
                    float v0 = bf2f((u16)va[jj * 2])     + bf2f((u16)vb[jj * 2])     + rad * wl.x;
                    float v1 = bf2f((u16)va[jj * 2 + 1]) + bf2f((u16)vb[jj * 2 + 1]) + rad * wl.y;
                    pk[jj] = pack2(fast_silu(v0), fast_silu(v1));
                }
                int chunk = (w * 4 + k) ^ sw;
                *(uint4*)&S.m1[lane * 136 + chunk * 8] =
                    make_uint4(pk[0], pk[1], pk[2], pk[3]);
            }
        }
        __syncthreads();
        // ---- layer2 MFMA: all 4 m-tiles, then barrier so m1 can be reused ----
        f32x4 acc2[4][2];
        #pragma unroll
        for (int mt = 0; mt < 4; mt++) {
            acc2[mt][0] = (f32x4){0,0,0,0};
            acc2[mt][1] = (f32x4){0,0,0,0};
            const int rs = mt * 2 + (m >> 3);
            const int row = mt * 16 + m;
            #pragma unroll
            for (int t = 0; t < 4; t++) {
                bf16x8 a = *(const bf16x8*)&S.m1[row * 136 + ((t * 4 + quad) ^ rs) * 8];
                acc2[mt][0] = mfma16(a, bw2[t][0], acc2[mt][0]);
                acc2[mt][1] = mfma16(a, bw2[t][1], acc2[mt][1]);
            }
        }
        __syncthreads();   // all m1 reads done; m1 space becomes msgT
        // ---- epilogue: msg row-major + msgT (col-major, packed b64 into m1) ----
        #pragma unroll
        for (int mt = 0; mt < 4; mt++) {
            #pragma unroll
            for (int cc = 0; cc < 2; cc++) {
                int col = (2 * w + cc) * 16 + m;
                int R = mt * 16 + quad * 4;
                float v0 = fast_silu(acc2[mt][cc][0] + b2v[cc]);
                float v1 = fast_silu(acc2[mt][cc][1] + b2v[cc]);
                float v2 = fast_silu(acc2[mt][cc][2] + b2v[cc]);
                float v3 = fast_silu(acc2[mt][cc][3] + b2v[cc]);
                S.msg[(R + 0) * 136 + col] = f2bf(v0);
                S.msg[(R + 1) * 136 + col] = f2bf(v1);
                S.msg[(R + 2) * 136 + col] = f2bf(v2);
                S.msg[(R + 3) * 136 + col] = f2bf(v3);
                uint2 pk = make_uint2(pack2(v0, v1), pack2(v2, v3));
                *(uint2*)&S.m1[col * 68 + R] = pk;
            }
        }
        __syncthreads();
        // ---- pos head: pc = silu(msg @ pW1 + pb1) @ pW2 (per-wave partials) ----
        #pragma unroll
        for (int mt = 0; mt < 4; mt++) {
            f32x4 acc0 = (f32x4){0,0,0,0}, acc1 = (f32x4){0,0,0,0};
            #pragma unroll
            for (int t = 0; t < 4; t++) {
                bf16x8 a = *(const bf16x8*)&S.msg[(mt * 16 + m) * 136 + t * 32 + ksub];
                acc0 = mfma16(a, bp1[t][0], acc0);
                acc1 = mfma16(a, bp1[t][1], acc1);
            }
            float p4[4];
            #pragma unroll
            for (int rr = 0; rr < 4; rr++)
                p4[rr] = fast_silu(acc0[rr] + pb1v[0]) * pw2v[0]
                       + fast_silu(acc1[rr] + pb1v[1]) * pw2v[1];
            #pragma unroll
            for (int mask = 1; mask < 16; mask <<= 1) {
                #pragma unroll
                for (int rr = 0; rr < 4; rr++) p4[rr] += __shfl_xor(p4[rr], mask);
            }
            if (m == 0) {
                #pragma unroll
                for (int rr = 0; rr < 4; rr++)
                    S.pcpart[w][mt * 16 + quad * 4 + rr] = p4[rr];
            }
        }
        // ---- agg: vectorized segment walk over msgT + ballot boundary mask ----
        {
            int half = tid >> 7, col = tid & 127;
            int r0 = half * 32;
            u32 mask = S.segmask[half];
            bf16x8 mrow[4];
            #pragma unroll
            for (int k = 0; k < 4; k++)
                mrow[k] = *(const bf16x8*)&S.m1[col * 68 + r0 + k * 8];
            float a = 0.f;
            int cur = S.rcvloc[r0];
            #pragma unroll
            for (int i = 0; i < 32; i++) {
                if (i > 0 && ((mask >> i) & 1u)) {
                    atomicAdd(&agg[(size_t)cur * 128 + col], a);
                    a = 0.f;
                    cur = S.rcvloc[r0 + i];
                }
                a += bf2f((u16)mrow[i >> 3][i & 7]);
            }
            atomicAdd(&agg[(size_t)cur * 128 + col], a);
        }
        __syncthreads();
        if (tid < 192) {
            int ee = tid / 3, c = tid - ee * 3;
            float pc = S.pcpart[0][ee] + S.pcpart[1][ee] + S.pcpart[2][ee] + S.pcpart[3][ee];
            float tr = S.diff[ee][c] * pc;
            tr = fminf(fmaxf(tr, -100.f), 100.f);
            atomicAdd(&posacc[S.sndloc[ee] * 3 + c], tr);
        }
    }
}

// Node MLP (+ fused pos output): h_new = h + (silu([h,agg]@nW1+nb1)@nW2+nb2)
__global__ __launch_bounds__(256, 4) void node_kernel(
    const u16* __restrict__ P, const float* __restrict__ h,
    const float* __restrict__ agg,
    const u16* __restrict__ nW1bT, const float* __restrict__ nb1,
    const u16* __restrict__ nW2T, const float* __restrict__ nb2,
    const float* __restrict__ pos, const float* __restrict__ posacc,
    float* __restrict__ out)
{
    __shared__ alignas(16) u16 m1[64 * 136];
    const int tid  = threadIdx.x;
    const int w    = tid >> 6;
    const int lane = tid & 63;
    const int m    = lane & 15;
    const int quad = lane >> 4;
    const int ksub = quad * 8;

    bf16x8 bw1[4][2], bw2[4][2];
    float b1v[2], b2v[2];
    #pragma unroll
    for (int cc = 0; cc < 2; cc++) {
        int col = (2 * w + cc) * 16 + m;
        #pragma unroll
        for (int t = 0; t < 4; t++) {
            bw1[t][cc] = ld8(nW1bT + col * 128 + t * 32 + ksub);
            bw2[t][cc] = ld8(nW2T + col * 128 + t * 32 + ksub);
        }
        b1v[cc] = nb1[col];
        b2v[cc] = nb2[col];
    }
    const int base = blockIdx.x * 64;
    #pragma unroll
    for (int mt = 0; mt < 4; mt++) {
        int nm = base + mt * 16 + m;
        if (nm >= NNODES) nm = NNODES - 1;
        f32x4 acc0 = (f32x4){0,0,0,0}, acc1 = (f32x4){0,0,0,0};
        #pragma unroll
        for (int t = 0; t < 4; t++) {
            const float* ap = agg + (size_t)nm * 128 + t * 32 + ksub;
            f32x4 lo = *(const f32x4*)ap;
            f32x4 hi = *(const f32x4*)(ap + 4);
            bf16x8 a;
            #pragma unroll
            for (int j = 0; j < 4; j++) {
                a[j]     = (short)f2bf(lo[j]);
                a[4 + j] = (short)f2bf(hi[j]);
            }
            acc0 = mfma16(a, bw1[t][0], acc0);
            acc1 = mfma16(a, bw1[t][1], acc1);
        }
        #pragma unroll
        for (int cc = 0; cc < 2; cc++) {
            f32x4 acc = cc ? acc1 : acc0;
            int col = (2 * w + cc) * 16 + m;
            #pragma unroll
            for (int rr = 0; rr < 4; rr++) {
                int row = mt * 16 + quad * 4 + rr;
                int nrc = base + row; if (nrc >= NNODES) nrc = NNODES - 1;
                float v = acc[rr] + bf2f(P[(size_t)nrc * 384 + 256 + col]) + b1v[cc];
                m1[row * 136 + col] = f2bf(fast_silu(v));
            }
        }
    }
    __syncthreads();
    #pragma unroll
    for (int mt = 0; mt < 4; mt++) {
        f32x4 acc0 = (f32x4){0,0,0,0}, acc1 = (f32x4){0,0,0,0};
        #pragma unroll
        for (int t = 0; t < 4; t++) {
            bf16x8 a = *(const bf16x8*)&m1[(mt * 16 + m) * 136 + t * 32 + ksub];
            acc0 = mfma16(a, bw2[t][0], acc0);
            acc1 = mfma16(a, bw2[t][1], acc1);
        }
        #pragma unroll
        for (int cc = 0; cc < 2; cc++) {
            f32x4 acc = cc ? acc1 : acc0;
            int col = (2 * w + cc) * 16 + m;
            #pragma unroll
            for (int rr = 0; rr < 4; rr++) {
                int nr = base + mt * 16 + quad * 4 + rr;
                if (nr < NNODES)
                    out[(size_t)nr * 128 + col] = acc[rr] + b2v[cc] + h[(size_t)nr * 128 + col];
            }
        }
    }
    if (tid < 192) {
        int i = blockIdx.x * 192 + tid;
        if (i < NNODES * 3) out[NNODES * 128 + i] = pos[i] + posacc[i];
    }
}

extern "C" void kernel_launch(void* const* d_in, const int* in_sizes, int n_in,
                              void* d_out, int out_size, void* d_ws, size_t ws_size,
                              hipStream_t stream) {
    (void)in_sizes; (void)n_in; (void)out_size; (void)ws_size;
    const float* h   = (const float*)d_in[0];
    const float* pos = (const float*)d_in[1];
    const int*   snd = (const int*)d_in[2];
    const int*   rcv = (const int*)d_in[3];
    const float* eW1 = (const float*)d_in[4];
    const float* eb1 = (const float*)d_in[5];
    const float* eW2 = (const float*)d_in[6];
    const float* eb2 = (const float*)d_in[7];
    const float* nW1 = (const float*)d_in[8];
    const float* nb1 = (const float*)d_in[9];
    const float* nW2 = (const float*)d_in[10];
    const float* nb2 = (const float*)d_in[11];
    const float* pW1 = (const float*)d_in[12];
    const float* pb1 = (const float*)d_in[13];
    const float* pW2 = (const float*)d_in[14];
    float* out = (float*)d_out;

    // ---- ws layout: one contiguous zeroed region first ----
    float* agg    = (float*)d_ws;                       // [N*128] f32
    float* posacc = agg + (size_t)NNODES * 128;         // [N*3]
    int* counts = (int*)(posacc + (size_t)NNODES * 3);  // [50048]
    int* flags  = counts + 50048;                       // [256]
    // non-zeroed:
    int* cursor = flags + 256;                          // [50048]
    int* perm   = cursor + 50048;                       // [E]
    u16* P      = (u16*)(perm + NEDGES);                // [N*384] bf16
    u16* eW2T   = P + (size_t)NNODES * 384;             // [128*128]
    u16* pW1T   = eW2T + 128 * 128;
    u16* nW1bT  = pW1T + 128 * 128;
    u16* nW2T   = nW1bT + 128 * 128;

    size_t zero_bytes = ((size_t)NNODES * 131 + 50048 + 256) * sizeof(float);
    hipMemsetAsync(agg, 0, zero_bytes, stream);

    prep_kernel<<<TRN_BLOCKS + (NEDGES + 255) / 256, 256, 0, stream>>>(
        eW2, pW1, nW1, nW2, eW2T, pW1T, nW1bT, nW2T, rcv, counts);

    scan_chained<<<SCAN_BLOCKS, 256, 0, stream>>>(counts, cursor, flags);

    gemm_p<<<GP_BLOCKS, 256, 0, stream>>>(h, eW1, nW1, eb1, P);

    scatter_kernel<<<(NEDGES + 255) / 256, 256, 0, stream>>>(rcv, cursor, perm);

    edge_kernel<<<EB, 256, 0, stream>>>(
        P, pos, snd, rcv, perm,
        eW1 + 256 * 128,
        eW2T, eb2, pW1T, pb1, pW2,
        agg, posacc);

    node_kernel<<<GP_BLOCKS, 256, 0, stream>>>(
        P, h, agg, nW1bT, nb1, nW2T, nb2, pos, posacc, out);
}

// Round 7
// 534.288 us; speedup vs baseline: 1.1245x; 1.1245x over previous
//
#include <hip/hip_runtime.h>
#include <hip/hip_bf16.h>

#define NNODES 50000
#define NEDGES 800000
#define EB 1024           // edge grid: 4 blocks/CU resident
#define TRN_BLOCKS 256    // 4 x 128x128 transposes / 256
#define HIST_BLOCKS 3125  // ceil(800000/256)
#define GP_BLOCKS 782     // ceil(50000/64)

typedef short bf16x8 __attribute__((ext_vector_type(8)));
typedef float f32x4 __attribute__((ext_vector_type(4)));
typedef unsigned short u16;
typedef unsigned int u32;

__device__ __forceinline__ u16 f2bf(float f) {
    __hip_bfloat16 b = __float2bfloat16(f);
    return *reinterpret_cast<u16*>(&b);
}
__device__ __forceinline__ float bf2f(u16 v) {
    u32 u = ((u32)v) << 16;
    return __uint_as_float(u);
}
__device__ __forceinline__ u32 pack2(float a, float b) {
    __hip_bfloat162 t = __float22bfloat162_rn(float2{a, b});
    return *reinterpret_cast<u32*>(&t);
}
__device__ __forceinline__ float fast_silu(float x) {
    float e = __builtin_amdgcn_exp2f(-1.442695040888963f * x);
    return x * __builtin_amdgcn_rcpf(1.0f + e);
}
__device__ __forceinline__ bf16x8 ld8(const u16* p) {
    return *(const bf16x8*)p;
}
__device__ __forceinline__ f32x4 mfma16(bf16x8 a, bf16x8 b, f32x4 c) {
    return __builtin_amdgcn_mfma_f32_16x16x32_bf16(a, b, c, 0, 0, 0);
}

// ---- prep_all: [0,256) transposes | [256,3381) histogram | [3381,4163) gemm_p + zero agg ----
__global__ __launch_bounds__(256) void prep_all(
    const float* __restrict__ eW2, const float* __restrict__ pW1,
    const float* __restrict__ nW1, const float* __restrict__ nW2,
    u16* __restrict__ eW2T, u16* __restrict__ pW1T,
    u16* __restrict__ nW1bT, u16* __restrict__ nW2T,
    const int* __restrict__ rcv, int* __restrict__ counts,
    const float* __restrict__ h, const float* __restrict__ eW1,
    const float* __restrict__ eb1, u16* __restrict__ P,
    float* __restrict__ agg, float* __restrict__ posacc)
{
    const int b = blockIdx.x;
    const int tid = threadIdx.x;
    if (b < TRN_BLOCKS) {
        int i = b * 256 + tid;   // 0..65535
        int which = i >> 14, local = i & 16383;
        int c = local >> 7, k = local & 127;
        const float* src; u16* dst; int koff = 0;
        if (which == 0)      { src = eW2; dst = eW2T; }
        else if (which == 1) { src = pW1; dst = pW1T; }
        else if (which == 2) { src = nW1; dst = nW1bT; koff = 128; }
        else                 { src = nW2; dst = nW2T; }
        dst[local] = f2bf(src[(koff + k) * 128 + c]);
        return;
    }
    if (b < TRN_BLOCKS + HIST_BLOCKS) {
        int e = (b - TRN_BLOCKS) * 256 + tid;
        if (e < NEDGES) atomicAdd(&counts[rcv[e]], 1);
        return;
    }
    // ---- gemm_p part + zero agg/posacc for this node slice ----
    const int gb = b - TRN_BLOCKS - HIST_BLOCKS;
    const int base = gb * 64;
    {   // zero agg slice: 64*128 floats
        size_t g0 = (size_t)base * 128 + tid * 32;
        #pragma unroll
        for (int o = 0; o < 8; o++) {
            size_t g = g0 + o * 4;
            if (g < (size_t)NNODES * 128) *(f32x4*)(agg + g) = (f32x4){0,0,0,0};
        }
        if (tid < 192) {
            int g = base * 3 + tid;
            if (g < NNODES * 3) posacc[g] = 0.f;
        }
    }
    const int w    = tid >> 6;
    const int lane = tid & 63;
    const int m    = lane & 15;
    const int quad = lane >> 4;
    const int ksub = quad * 8;

    bf16x8 bw[4][6];
    float bias[6];
    #pragma unroll
    for (int cc = 0; cc < 6; cc++) {
        int C = 96 * w + 16 * cc + m;
        const float* src; int koff, c;
        if (C < 128)      { src = eW1; koff = 0;   c = C;       bias[cc] = 0.5f * eb1[C]; }
        else if (C < 256) { src = eW1; koff = 128; c = C - 128; bias[cc] = 0.5f * eb1[C - 128]; }
        else              { src = nW1; koff = 0;   c = C - 256; bias[cc] = 0.f; }
        #pragma unroll
        for (int t = 0; t < 4; t++)
            #pragma unroll
            for (int j = 0; j < 8; j++)
                bw[t][cc][j] = (short)f2bf(src[(koff + t * 32 + ksub + j) * 128 + c]);
    }
    #pragma unroll
    for (int mt = 0; mt < 4; mt++) {
        int nm = base + mt * 16 + m;
        if (nm >= NNODES) nm = NNODES - 1;
        bf16x8 afr[4];
        #pragma unroll
        for (int t = 0; t < 4; t++) {
            const float* ap = h + (size_t)nm * 128 + t * 32 + ksub;
            f32x4 lo = *(const f32x4*)ap;
            f32x4 hi = *(const f32x4*)(ap + 4);
            #pragma unroll
            for (int j = 0; j < 4; j++) {
                afr[t][j]     = (short)f2bf(lo[j]);
                afr[t][4 + j] = (short)f2bf(hi[j]);
            }
        }
        f32x4 acc[6];
        #pragma unroll
        for (int cc = 0; cc < 6; cc++) acc[cc] = (f32x4){0,0,0,0};
        #pragma unroll
        for (int t = 0; t < 4; t++)
            #pragma unroll
            for (int cc = 0; cc < 6; cc++)
                acc[cc] = mfma16(afr[t], bw[t][cc], acc[cc]);
        #pragma unroll
        for (int cc = 0; cc < 6; cc++) {
            int C = 96 * w + 16 * cc + m;
            #pragma unroll
            for (int r = 0; r < 4; r++) {
                int nr = base + mt * 16 + quad * 4 + r;
                if (nr < NNODES) P[(size_t)nr * 384 + C] = f2bf(acc[cc][r] + bias[cc]);
            }
        }
    }
}

// ---- single-block exclusive scan over 50048 counts (two-pass per thread) ----
__global__ __launch_bounds__(1024) void scan_single(const int* __restrict__ counts,
                                                    int* __restrict__ cursor) {
    __shared__ int part[1024];
    const int PER = 49;          // 1024*49 = 50176 >= 50048
    int tx = threadIdx.x;
    int base = tx * PER;
    int s = 0;
    for (int i = 0; i < PER; i++) {
        int idx = base + i;
        if (idx < NNODES) s += counts[idx];
    }
    part[tx] = s;
    __syncthreads();
    for (int off = 1; off < 1024; off <<= 1) {
        int t = (tx >= off) ? part[tx - off] : 0;
        __syncthreads();
        part[tx] += t;
        __syncthreads();
    }
    int run = (tx > 0) ? part[tx - 1] : 0;
    for (int i = 0; i < PER; i++) {
        int idx = base + i;
        if (idx < NNODES) {
            cursor[idx] = run;
            run += counts[idx];
        }
    }
}

__global__ void scatter_kernel(const int* __restrict__ rcv, int* __restrict__ cursor,
                               int* __restrict__ perm) {
    int e = blockIdx.x * 256 + threadIdx.x;
    if (e < NEDGES) {
        int p = atomicAdd(&cursor[rcv[e]], 1);
        perm[p] = e;
    }
}

struct __align__(16) EdgeLds {
    u16   m1[64 * 136];       // XOR-swizzled 8-col chunks
    u16   msg[64 * 136];
    float diff[64][4];
    float pcpart[4][64];
    float wlast[128];
    float radial[64];
    int   sndloc[64];
    int   rcvloc[64];
};   // ~38 KB -> 4 blocks/CU

__global__ __launch_bounds__(256, 4) void edge_kernel(
    const u16* __restrict__ P, const float* __restrict__ pos,
    const int* __restrict__ snd, const int* __restrict__ rcv,
    const int* __restrict__ perm,
    const float* __restrict__ eW1last,
    const u16* __restrict__ eW2T, const float* __restrict__ eb2,
    const u16* __restrict__ pW1T, const float* __restrict__ pb1,
    const float* __restrict__ pW2,
    float* __restrict__ agg, float* __restrict__ posacc)
{
    __shared__ EdgeLds S;
    const int tid  = threadIdx.x;
    const int w    = tid >> 6;
    const int lane = tid & 63;
    const int m    = lane & 15;
    const int quad = lane >> 4;
    const int ksub = quad * 8;

    bf16x8 bw2[4][2], bp1[4][2];
    float b2v[2], pb1v[2], pw2v[2];
    #pragma unroll
    for (int cc = 0; cc < 2; cc++) {
        int col = (2 * w + cc) * 16 + m;
        #pragma unroll
        for (int t = 0; t < 4; t++) {
            bw2[t][cc] = ld8(eW2T + col * 128 + t * 32 + ksub);
            bp1[t][cc] = ld8(pW1T + col * 128 + t * 32 + ksub);
        }
        b2v[cc]  = eb2[col];
        pb1v[cc] = pb1[col];
        pw2v[cc] = pW2[col];
    }
    if (tid < 128) S.wlast[tid] = eW1last[tid];

    for (int base = blockIdx.x * 64; base < NEDGES; base += gridDim.x * 64) {
        __syncthreads();
        const int e = lane;
        int eg = perm[base + e];
        int s = snd[eg], r = rcv[eg];
        if (tid < 64) {
            S.sndloc[tid] = s; S.rcvloc[tid] = r;
            float rad = 0.f;
            #pragma unroll
            for (int c = 0; c < 3; c++) {
                float d = pos[s * 3 + c] - pos[r * 3 + c];
                S.diff[tid][c] = d;
                rad += d * d;
            }
            S.radial[tid] = rad;
        }
        __syncthreads();
        // ---- layer1: m1 = silu(Pa[s] + Pb[r] + rad*wlast)  (bias pre-folded) ----
        {
            float rad = S.radial[e];
            const u16* pa = P + (size_t)s * 384 + w * 32;
            const u16* pb = P + (size_t)r * 384 + 128 + w * 32;
            const int sw = e >> 3;
            #pragma unroll
            for (int k = 0; k < 4; k++) {
                bf16x8 va = ld8(pa + k * 8);
                bf16x8 vb = ld8(pb + k * 8);
                u32 pk[4];
                #pragma unroll
                for (int jj = 0; jj < 4; jj++) {
                    int col = w * 32 + k * 8 + jj * 2;
                    float2 wl = *(const float2*)&S.wlast[col];
                    float v0 = bf2f((u16)va[jj * 2])     + bf2f((u16)vb[jj * 2])     + rad * wl.x;
                    float v1 = bf2f((u16)va[jj * 2 + 1]) + bf2f((u16)vb[jj * 2 + 1]) + rad * wl.y;
                    pk[jj] = pack2(fast_silu(v0), fast_silu(v1));
                }
                int chunk = (w * 4 + k) ^ sw;
                *(uint4*)&S.m1[e * 136 + chunk * 8] =
                    make_uint4(pk[0], pk[1], pk[2], pk[3]);
            }
        }
        __syncthreads();
        // ---- layer2: msg = silu(m1 @ eW2 + b2) ----
        #pragma unroll
        for (int mt = 0; mt < 4; mt++) {
            const int rs = mt * 2 + (m >> 3);
            const int row = mt * 16 + m;
            f32x4 acc0 = (f32x4){0,0,0,0}, acc1 = (f32x4){0,0,0,0};
            #pragma unroll
            for (int t = 0; t < 4; t++) {
                bf16x8 a = *(const bf16x8*)&S.m1[row * 136 + ((t * 4 + quad) ^ rs) * 8];
                acc0 = mfma16(a, bw2[t][0], acc0);
                acc1 = mfma16(a, bw2[t][1], acc1);
            }
            #pragma unroll
            for (int cc = 0; cc < 2; cc++) {
                f32x4 acc = cc ? acc1 : acc0;
                int col = (2 * w + cc) * 16 + m;
                #pragma unroll
                for (int rr = 0; rr < 4; rr++) {
                    int orow = mt * 16 + quad * 4 + rr;
                    S.msg[orow * 136 + col] = f2bf(fast_silu(acc[rr] + b2v[cc]));
                }
            }
        }
        __syncthreads();
        // ---- pos head: pc = silu(msg @ pW1 + pb1) @ pW2 (per-wave partials) ----
        #pragma unroll
        for (int mt = 0; mt < 4; mt++) {
            f32x4 acc0 = (f32x4){0,0,0,0}, acc1 = (f32x4){0,0,0,0};
            #pragma unroll
            for (int t = 0; t < 4; t++) {
                bf16x8 a = *(const bf16x8*)&S.msg[(mt * 16 + m) * 136 + t * 32 + ksub];
                acc0 = mfma16(a, bp1[t][0], acc0);
                acc1 = mfma16(a, bp1[t][1], acc1);
            }
            float p4[4];
            #pragma unroll
            for (int rr = 0; rr < 4; rr++)
                p4[rr] = fast_silu(acc0[rr] + pb1v[0]) * pw2v[0]
                       + fast_silu(acc1[rr] + pb1v[1]) * pw2v[1];
            #pragma unroll
            for (int mask = 1; mask < 16; mask <<= 1) {
                #pragma unroll
                for (int rr = 0; rr < 4; rr++) p4[rr] += __shfl_xor(p4[rr], mask);
            }
            if (m == 0) {
                #pragma unroll
                for (int rr = 0; rr < 4; rr++)
                    S.pcpart[w][mt * 16 + quad * 4 + rr] = p4[rr];
            }
        }
        // ---- agg: segment walk over receiver-sorted rows ----
        {
            int half = tid >> 7, col = tid & 127;
            int r0 = half * 32;
            float a = 0.f;
            int cur = S.rcvloc[r0];
            for (int rr = r0; rr < r0 + 32; ++rr) {
                int rc = S.rcvloc[rr];
                if (rc != cur) {
                    atomicAdd(&agg[(size_t)cur * 128 + col], a);
                    a = 0.f; cur = rc;
                }
                a += bf2f(S.msg[rr * 136 + col]);
            }
            atomicAdd(&agg[(size_t)cur * 128 + col], a);
        }
        __syncthreads();
        if (tid < 192) {
            int ee = tid / 3, c = tid - ee * 3;
            float pc = S.pcpart[0][ee] + S.pcpart[1][ee] + S.pcpart[2][ee] + S.pcpart[3][ee];
            float tr = S.diff[ee][c] * pc;
            tr = fminf(fmaxf(tr, -100.f), 100.f);
            atomicAdd(&posacc[S.sndloc[ee] * 3 + c], tr);
        }
    }
}

// Node MLP (+ fused pos output): h_new = h + (silu([h,agg]@nW1+nb1)@nW2+nb2)
__global__ __launch_bounds__(256, 4) void node_kernel(
    const u16* __restrict__ P, const float* __restrict__ h,
    const float* __restrict__ agg,
    const u16* __restrict__ nW1bT, const float* __restrict__ nb1,
    const u16* __restrict__ nW2T, const float* __restrict__ nb2,
    const float* __restrict__ pos, const float* __restrict__ posacc,
    float* __restrict__ out)
{
    __shared__ alignas(16) u16 m1[64 * 136];
    const int tid  = threadIdx.x;
    const int w    = tid >> 6;
    const int lane = tid & 63;
    const int m    = lane & 15;
    const int quad = lane >> 4;
    const int ksub = quad * 8;

    bf16x8 bw1[4][2], bw2[4][2];
    float b1v[2], b2v[2];
    #pragma unroll
    for (int cc = 0; cc < 2; cc++) {
        int col = (2 * w + cc) * 16 + m;
        #pragma unroll
        for (int t = 0; t < 4; t++) {
            bw1[t][cc] = ld8(nW1bT + col * 128 + t * 32 + ksub);
            bw2[t][cc] = ld8(nW2T + col * 128 + t * 32 + ksub);
        }
        b1v[cc] = nb1[col];
        b2v[cc] = nb2[col];
    }
    const int base = blockIdx.x * 64;
    #pragma unroll
    for (int mt = 0; mt < 4; mt++) {
        int nm = base + mt * 16 + m;
        if (nm >= NNODES) nm = NNODES - 1;
        f32x4 acc0 = (f32x4){0,0,0,0}, acc1 = (f32x4){0,0,0,0};
        #pragma unroll
        for (int t = 0; t < 4; t++) {
            const float* ap = agg + (size_t)nm * 128 + t * 32 + ksub;
            f32x4 lo = *(const f32x4*)ap;
            f32x4 hi = *(const f32x4*)(ap + 4);
            bf16x8 a;
            #pragma unroll
            for (int j = 0; j < 4; j++) {
                a[j]     = (short)f2bf(lo[j]);
                a[4 + j] = (short)f2bf(hi[j]);
            }
            acc0 = mfma16(a, bw1[t][0], acc0);
            acc1 = mfma16(a, bw1[t][1], acc1);
        }
        #pragma unroll
        for (int cc = 0; cc < 2; cc++) {
            f32x4 acc = cc ? acc1 : acc0;
            int col = (2 * w + cc) * 16 + m;
            #pragma unroll
            for (int rr = 0; rr < 4; rr++) {
                int row = mt * 16 + quad * 4 + rr;
                int nrc = base + row; if (nrc >= NNODES) nrc = NNODES - 1;
                float v = acc[rr] + bf2f(P[(size_t)nrc * 384 + 256 + col]) + b1v[cc];
                m1[row * 136 + col] = f2bf(fast_silu(v));
            }
        }
    }
    __syncthreads();
    #pragma unroll
    for (int mt = 0; mt < 4; mt++) {
        f32x4 acc0 = (f32x4){0,0,0,0}, acc1 = (f32x4){0,0,0,0};
        #pragma unroll
        for (int t = 0; t < 4; t++) {
            bf16x8 a = *(const bf16x8*)&m1[(mt * 16 + m) * 136 + t * 32 + ksub];
            acc0 = mfma16(a, bw2[t][0], acc0);
            acc1 = mfma16(a, bw2[t][1], acc1);
        }
        #pragma unroll
        for (int cc = 0; cc < 2; cc++) {
            f32x4 acc = cc ? acc1 : acc0;
            int col = (2 * w + cc) * 16 + m;
            #pragma unroll
            for (int rr = 0; rr < 4; rr++) {
                int nr = base + mt * 16 + quad * 4 + rr;
                if (nr < NNODES)
                    out[(size_t)nr * 128 + col] = acc[rr] + b2v[cc] + h[(size_t)nr * 128 + col];
            }
        }
    }
    if (tid < 192) {
        int i = blockIdx.x * 192 + tid;
        if (i < NNODES * 3) out[NNODES * 128 + i] = pos[i] + posacc[i];
    }
}

extern "C" void kernel_launch(void* const* d_in, const int* in_sizes, int n_in,
                              void* d_out, int out_size, void* d_ws, size_t ws_size,
                              hipStream_t stream) {
    (void)in_sizes; (void)n_in; (void)out_size; (void)ws_size;
    const float* h   = (const float*)d_in[0];
    const float* pos = (const float*)d_in[1];
    const int*   snd = (const int*)d_in[2];
    const int*   rcv = (const int*)d_in[3];
    const float* eW1 = (const float*)d_in[4];
    const float* eb1 = (const float*)d_in[5];
    const float* eW2 = (const float*)d_in[6];
    const float* eb2 = (const float*)d_in[7];
    const float* nW1 = (const float*)d_in[8];
    const float* nb1 = (const float*)d_in[9];
    const float* nW2 = (const float*)d_in[10];
    const float* nb2 = (const float*)d_in[11];
    const float* pW1 = (const float*)d_in[12];
    const float* pb1 = (const float*)d_in[13];
    const float* pW2 = (const float*)d_in[14];
    float* out = (float*)d_out;

    float* agg    = (float*)d_ws;                       // [N*128] f32 (zeroed by prep_all)
    float* posacc = agg + (size_t)NNODES * 128;         // [N*3]   (zeroed by prep_all)
    int* counts = (int*)(posacc + (size_t)NNODES * 3);  // [50048] (zeroed by memset)
    int* cursor = counts + 50048;                       // [50048]
    int* perm   = cursor + 50048;                       // [E]
    u16* P      = (u16*)(perm + NEDGES);                // [N*384] bf16
    u16* eW2T   = P + (size_t)NNODES * 384;             // [128*128]
    u16* pW1T   = eW2T + 128 * 128;
    u16* nW1bT  = pW1T + 128 * 128;
    u16* nW2T   = nW1bT + 128 * 128;

    hipMemsetAsync(counts, 0, 50048 * sizeof(int), stream);

    prep_all<<<TRN_BLOCKS + HIST_BLOCKS + GP_BLOCKS, 256, 0, stream>>>(
        eW2, pW1, nW1, nW2, eW2T, pW1T, nW1bT, nW2T,
        rcv, counts, h, eW1, eb1, P, agg, posacc);

    scan_single<<<1, 1024, 0, stream>>>(counts, cursor);

    scatter_kernel<<<(NEDGES + 255) / 256, 256, 0, stream>>>(rcv, cursor, perm);

    edge_kernel<<<EB, 256, 0, stream>>>(
        P, pos, snd, rcv, perm,
        eW1 + 256 * 128,
        eW2T, eb2, pW1T, pb1, pW2,
        agg, posacc);

    node_kernel<<<GP_BLOCKS, 256, 0, stream>>>(
        P, h, agg, nW1bT, nb1, nW2T, nb2, pos, posacc, out);
}